// Round 5
// baseline (216.269 us; speedup 1.0000x reference)
//
#include <hip/hip_runtime.h>

// Problem constants (T=512, B=16 -> 8192 tokens), all tensors float32
#define NTOK 8192
#define CDIM 512
#define NB   8
#define RD   64
#define OD   512

// Phase A geometry: 512 blocks x 128 threads (2 waves), 16 tokens/block,
// 8 tokens per wave.
#define TPB_A 16
#define XPAD  4                    // pad x rows to 516 f32: float4-aligned
#define XROW  (CDIM + XPAD)        // 516
#define XROW4 (XROW / 4)           // 129

typedef unsigned char u8;

__device__ __forceinline__ float4 f4add(float4 a, float4 b) {
    return make_float4(a.x + b.x, a.y + b.y, a.z + b.z, a.w + b.w);
}
// Exact expression shape of the verified kernel: ((wx*xx + wy*xy) + wz*xz) + ww*xw
__device__ __forceinline__ float dot4(float4 a, float4 b) {
    return a.x * b.x + a.y * b.y + a.z * b.z + a.w * b.w;
}

// ---------------------------------------------------------------------------
// Phase A. Round-4 post-mortem: across 5 structural variants, VALUBusy*dur is
// constant (~11.5 us) and dur is pinned at 52-58 us -> a shared pipe outside
// the VALUBusy counter is saturated. The invariant op class is the f64 logit
// math (~1.57M f64 wave-ops/dispatch on the slow DP pipe). This version
// replaces f64 with a compensated f32 Dot2 (fmaf product error + branchless
// TwoSum accumulation, error ~1e-13 => same sign decisions as f64) running
// entirely on the full-rate f32 pipe. v-loop and everything else are verbatim
// from the verified round-3 kernel (best wall, zero bank conflicts).
// ---------------------------------------------------------------------------
__global__ __launch_bounds__(128, 2) void phaseA(
    const float* __restrict__ x, const float* __restrict__ map_w,
    const float* __restrict__ map_b, const float* __restrict__ w1,
    u8* __restrict__ q_out, float* __restrict__ v_out,
    float* __restrict__ loss_out)
{
    const int t    = threadIdx.x;
    const int tok0 = blockIdx.x * TPB_A;
    __shared__ __align__(16) float xs[TPB_A * XROW];   // 33 KB

    // ---- stage x tile (16 independent float4 loads/thread, coalesced) ----
    const float4* xsrc = (const float4*)(x + (size_t)tok0 * CDIM);
    #pragma unroll
    for (int i = t; i < TPB_A * (CDIM / 4); i += 128) {
        int r = i >> 7, c = i & 127;                    // CDIM/4 = 128
        *((float4*)(xs + r * XROW) + c) = xsrc[i];
    }
    __syncthreads();

    // ---- logits: one thread per (token,bit), compensated f32 Dot2 ----
    // p = m*x; ep = fmaf(m,x,-p) recovers the product rounding error;
    // TwoSum (Knuth, branchless) accumulates p exactly into (s, c).
    // Total error ~ u^2 * sum|p| ~ 1e-13: sign decisions match f64.
    {
        const int bit = t & 7, tk = t >> 3;             // tk in 0..15
        const float4* m4 = (const float4*)(map_w + (size_t)bit * CDIM);
        const float4* x4 = (const float4*)xs + tk * XROW4;
        float s = 0.f, c = 0.f;
        for (int j = 0; j < CDIM / 4; ++j) {
            float4 m = m4[j], xv = x4[j];
#define ACC(MM, XX) { float p  = (MM) * (XX);                        \
            float ep = __builtin_fmaf((MM), (XX), -p);               \
            float tt = s + p;                                        \
            float z  = tt - s;                                       \
            c += ((s - (tt - z)) + (p - z)) + ep;                    \
            s  = tt; }
            ACC(m.x, xv.x) ACC(m.y, xv.y) ACC(m.z, xv.z) ACC(m.w, xv.w)
#undef ACC
        }
        const double k = (double)s + ((double)c + (double)map_b[bit]);
        unsigned long long m = __ballot(k > 0.0);
        const int lane = t & 63;
        if ((lane & 7) == 0) {
            int g = lane >> 3;                          // local token in wave
            q_out[tok0 + tk] = (u8)((m >> (g * 8)) & 0xFFull);
        }
    }

    // ---- v: wave tg -> tokens tg*8..tg*8+7, lane r = w1 row ----
    // ping-pong named-register prefetch of the w1 row stream (round-3 verbatim)
    {
        const int r  = t & 63;
        const int tg = t >> 6;                          // 0..1
        const float4* w4 = (const float4*)(w1 + (size_t)r * CDIM);
        const float4* xq = (const float4*)xs + (size_t)(tg * 8) * XROW4;
        float acc0 = 0.f, acc1 = 0.f, acc2 = 0.f, acc3 = 0.f;
        float acc4 = 0.f, acc5 = 0.f, acc6 = 0.f, acc7 = 0.f;

#define CONSUME(WV, J) { const int jj = (J);                       \
        acc0 += dot4(WV, xq[jj]);                                  \
        acc1 += dot4(WV, xq[1 * XROW4 + jj]);                      \
        acc2 += dot4(WV, xq[2 * XROW4 + jj]);                      \
        acc3 += dot4(WV, xq[3 * XROW4 + jj]);                      \
        acc4 += dot4(WV, xq[4 * XROW4 + jj]);                      \
        acc5 += dot4(WV, xq[5 * XROW4 + jj]);                      \
        acc6 += dot4(WV, xq[6 * XROW4 + jj]);                      \
        acc7 += dot4(WV, xq[7 * XROW4 + jj]); }

        float4 A0 = w4[0], A1 = w4[1], A2 = w4[2], A3 = w4[3];
        float4 B0, B1, B2, B3;
        for (int b = 0; b < CDIM / 4; b += 8) {
            B0 = w4[b + 4]; B1 = w4[b + 5]; B2 = w4[b + 6]; B3 = w4[b + 7];
            CONSUME(A0, b)     CONSUME(A1, b + 1)
            CONSUME(A2, b + 2) CONSUME(A3, b + 3)
            if (b + 8 < CDIM / 4) {
                A0 = w4[b + 8]; A1 = w4[b + 9]; A2 = w4[b + 10]; A3 = w4[b + 11];
            }
            CONSUME(B0, b + 4) CONSUME(B1, b + 5)
            CONSUME(B2, b + 6) CONSUME(B3, b + 7)
        }
#undef CONSUME

        float* vo = v_out + (size_t)(tok0 + tg * 8) * RD + r;   // coalesced
        vo[0 * RD] = acc0; vo[1 * RD] = acc1; vo[2 * RD] = acc2; vo[3 * RD] = acc3;
        vo[4 * RD] = acc4; vo[5 * RD] = acc5; vo[6 * RD] = acc6; vo[7 * RD] = acc7;
    }

    if (blockIdx.x == 0 && t == 0) loss_out[0] = 0.0f;  // loss = 0
}

// ---------------------------------------------------------------------------
// Phase B: verbatim from the round-3 kernel (best wall). 4 blocks per code,
// q_arr into registers first, 32 named weight float4s in flight across the
// scan, inner loop on 16 named fused-weight registers.
// ---------------------------------------------------------------------------
__global__ __launch_bounds__(128, 2) void phaseB(
    const u8* __restrict__ q_arr, const float* __restrict__ v_arr,
    const float* __restrict__ w21, const float* __restrict__ w22,
    const float* __restrict__ pwB, float* __restrict__ y)
{
    const int q  = blockIdx.x >> 2;
    const int qu = blockIdx.x & 3;
    const int t  = threadIdx.x;
    const int o  = qu * 128 + t;

    __shared__ unsigned short list[NTOK];   // 16 KB (worst case: all tokens one code)
    __shared__ int cnt;
    __shared__ __align__(16) float vs[8 * RD];  // 2 KB

    // ---- 1. q_arr into registers FIRST (retires before the weight burst) ----
    const uint4* qa = (const uint4*)q_arr;
    uint4 qv0 = qa[t], qv1 = qa[t + 128], qv2 = qa[t + 256], qv3 = qa[t + 384];

    // ---- 2. issue fused-weight loads (in flight during the scan) ----
    const float4* pa = (const float4*)w21 + (size_t)q * (OD * RD / 4) + (size_t)o * (RD / 4);
    const float4* pb = (const float4*)w22 + (size_t)(255 - q) * (OD * RD / 4) + (size_t)o * (RD / 4);
    float4 a0 = pa[0],  a1 = pa[1],  a2 = pa[2],  a3 = pa[3],
           a4 = pa[4],  a5 = pa[5],  a6 = pa[6],  a7 = pa[7],
           a8 = pa[8],  a9 = pa[9],  a10 = pa[10], a11 = pa[11],
           a12 = pa[12], a13 = pa[13], a14 = pa[14], a15 = pa[15];
    float4 b0 = pb[0],  b1 = pb[1],  b2 = pb[2],  b3 = pb[3],
           b4 = pb[4],  b5 = pb[5],  b6 = pb[6],  b7 = pb[7],
           b8 = pb[8],  b9 = pb[9],  b10 = pb[10], b11 = pb[11],
           b12 = pb[12], b13 = pb[13], b14 = pb[14], b15 = pb[15];

    if (t == 0) cnt = 0;
    __syncthreads();

    // ---- 3. scan from registers, LDS atomic append ----
#define CHK(WORD, SB, OFF) { unsigned uw = (WORD); \
    if ((int)(uw & 0xFFu)         == q) list[atomicAdd(&cnt, 1)] = (unsigned short)((SB) + (OFF));     \
    if ((int)((uw >> 8)  & 0xFFu) == q) list[atomicAdd(&cnt, 1)] = (unsigned short)((SB) + (OFF) + 1); \
    if ((int)((uw >> 16) & 0xFFu) == q) list[atomicAdd(&cnt, 1)] = (unsigned short)((SB) + (OFF) + 2); \
    if ((int)(uw >> 24)           == q) list[atomicAdd(&cnt, 1)] = (unsigned short)((SB) + (OFF) + 3); }
    { int sb = t * 16;          CHK(qv0.x, sb, 0) CHK(qv0.y, sb, 4) CHK(qv0.z, sb, 8) CHK(qv0.w, sb, 12) }
    { int sb = (t + 128) * 16;  CHK(qv1.x, sb, 0) CHK(qv1.y, sb, 4) CHK(qv1.z, sb, 8) CHK(qv1.w, sb, 12) }
    { int sb = (t + 256) * 16;  CHK(qv2.x, sb, 0) CHK(qv2.y, sb, 4) CHK(qv2.z, sb, 8) CHK(qv2.w, sb, 12) }
    { int sb = (t + 384) * 16;  CHK(qv3.x, sb, 0) CHK(qv3.y, sb, 4) CHK(qv3.z, sb, 8) CHK(qv3.w, sb, 12) }
#undef CHK
    __syncthreads();
    const int n = cnt;
    if (n == 0) return;                                 // uniform exit, no later syncs

    // ---- 4. combine fused weights into 16 named registers ----
    float4 w0 = f4add(a0, b0),  w1 = f4add(a1, b1),  w2 = f4add(a2, b2),  w3 = f4add(a3, b3),
           w4 = f4add(a4, b4),  w5 = f4add(a5, b5),  w6 = f4add(a6, b6),  w7 = f4add(a7, b7),
           w8 = f4add(a8, b8),  w9 = f4add(a9, b9),  w10 = f4add(a10, b10), w11 = f4add(a11, b11),
           w12 = f4add(a12, b12), w13 = f4add(a13, b13), w14 = f4add(a14, b14), w15 = f4add(a15, b15);
    const float bias = pwB[o];

    // ---- 5. stream tokens in batches of 8, token pairs (2 acc chains) ----
    const float4* v4 = (const float4*)v_arr;
    for (int base = 0; base < n; base += 8) {
        const int nb = min(8, n - base);
        if (t < nb * 16)                                // 8 tok x 16 float4 = 128 loads
            ((float4*)vs)[t] = v4[(size_t)list[base + (t >> 4)] * (RD / 4) + (t & 15)];
        __syncthreads();
        int i = 0;
        for (; i + 2 <= nb; i += 2) {
            const float4* p0 = (const float4*)vs + (size_t)i * 16;
            const float4* p1 = p0 + 16;
            float acc0 = bias, acc1 = bias;
#define STEP(J, W) { float4 u0 = p0[J], u1 = p1[J]; \
            acc0 += W.x * u0.x + W.y * u0.y + W.z * u0.z + W.w * u0.w; \
            acc1 += W.x * u1.x + W.y * u1.y + W.z * u1.z + W.w * u1.w; }
            STEP(0, w0)  STEP(1, w1)  STEP(2, w2)  STEP(3, w3)
            STEP(4, w4)  STEP(5, w5)  STEP(6, w6)  STEP(7, w7)
            STEP(8, w8)  STEP(9, w9)  STEP(10, w10) STEP(11, w11)
            STEP(12, w12) STEP(13, w13) STEP(14, w14) STEP(15, w15)
#undef STEP
            y[(size_t)list[base + i]     * OD + o] = acc0;
            y[(size_t)list[base + i + 1] * OD + o] = acc1;
        }
        if (i < nb) {                                   // odd tail
            const float4* p0 = (const float4*)vs + (size_t)i * 16;
            float acc0 = bias;
#define STEP1(J, W) { float4 u0 = p0[J]; \
            acc0 += W.x * u0.x + W.y * u0.y + W.z * u0.z + W.w * u0.w; }
            STEP1(0, w0)  STEP1(1, w1)  STEP1(2, w2)  STEP1(3, w3)
            STEP1(4, w4)  STEP1(5, w5)  STEP1(6, w6)  STEP1(7, w7)
            STEP1(8, w8)  STEP1(9, w9)  STEP1(10, w10) STEP1(11, w11)
            STEP1(12, w12) STEP1(13, w13) STEP1(14, w14) STEP1(15, w15)
#undef STEP1
            y[(size_t)list[base + i] * OD + o] = acc0;
        }
        __syncthreads();
    }
}

// ---------------------------------------------------------------------------
// Fallback (ws too small): workspace-free, one block per token.
// ---------------------------------------------------------------------------
__global__ __launch_bounds__(256) void mono(
    const float* __restrict__ x, const float* __restrict__ map_w,
    const float* __restrict__ map_b, const float* __restrict__ w1,
    const float* __restrict__ w21, const float* __restrict__ w22,
    const float* __restrict__ pwB, float* __restrict__ y)
{
    const int tok = blockIdx.x;
    const int t   = threadIdx.x;
    __shared__ float xsh[CDIM];
    __shared__ float vsh[RD];
    __shared__ int qsh;

    if (t == 0) qsh = 0;
    for (int i = t; i < CDIM; i += 256) xsh[i] = x[(size_t)tok * CDIM + i];
    __syncthreads();

    if (t < NB) {
        double a = 0.0;
        const float* mrow = map_w + (size_t)t * CDIM;
        for (int j = 0; j < CDIM; ++j) a += (double)mrow[j] * (double)xsh[j];
        a += (double)map_b[t];
        if (a > 0.0) atomicOr(&qsh, 1 << t);
    }
    if (t < RD) {
        const float* wrow = w1 + (size_t)t * CDIM;
        float acc = 0.f;
        for (int j = 0; j < CDIM; ++j) acc += wrow[j] * xsh[j];
        vsh[t] = acc;
    }
    __syncthreads();

    const int q = qsh;
    for (int o = t; o < OD; o += 256) {
        const float* pa = w21 + (size_t)q * (OD * RD) + (size_t)o * RD;
        const float* pb = w22 + (size_t)(255 - q) * (OD * RD) + (size_t)o * RD;
        float acc = pwB[o];
        for (int r = 0; r < RD; ++r) acc += (pa[r] + pb[r]) * vsh[r];
        y[(size_t)tok * OD + o] = acc;
    }
    if (tok == 0 && t == 0) y[(size_t)NTOK * OD] = 0.0f;
}

extern "C" void kernel_launch(void* const* d_in, const int* in_sizes, int n_in,
                              void* d_out, int out_size, void* d_ws, size_t ws_size,
                              hipStream_t stream) {
    const float* x     = (const float*)d_in[0];
    // d_in[1] = key: unused by the forward pass
    const float* map_w = (const float*)d_in[2];
    const float* map_b = (const float*)d_in[3];
    const float* w1    = (const float*)d_in[4];
    const float* w21   = (const float*)d_in[5];
    const float* w22   = (const float*)d_in[6];
    const float* pwB   = (const float*)d_in[7];
    float* out = (float*)d_out;

    const size_t need = (size_t)NTOK + (size_t)NTOK * RD * sizeof(float); // 8KB + 2MB
    if (ws_size >= need) {
        u8*    q_ws = (u8*)d_ws;
        float* v_ws = (float*)((char*)d_ws + NTOK);
        phaseA<<<NTOK / TPB_A, 128, 0, stream>>>(x, map_w, map_b, w1, q_ws, v_ws,
                                                 out + (size_t)NTOK * OD);
        phaseB<<<256 * 4, 128, 0, stream>>>(q_ws, v_ws, w21, w22, pwB, out);
    } else {
        mono<<<NTOK, 256, 0, stream>>>(x, map_w, map_b, w1, w21, w22, pwB, out);
    }
}

// Round 6
// 196.148 us; speedup vs baseline: 1.1026x; 1.1026x over previous
//
#include <hip/hip_runtime.h>

// Problem constants (T=512, B=16 -> 8192 tokens), all tensors float32
#define NTOK 8192
#define CDIM 512
#define NB   8
#define RD   64
#define OD   512

// Phase A geometry: 512 blocks x 128 threads (2 waves), 16 tokens/block,
// 8 tokens per wave.
#define TPB_A 16
#define XPAD  4                    // pad x rows to 516 f32: float4-aligned
#define XROW  (CDIM + XPAD)        // 516
#define XROW4 (XROW / 4)           // 129
#define SLJ   16                   // float4-columns of w1 per LDS slice
#define NSLICE (128 / SLJ)         // 8
#define WSTR  65                   // padded float4 stride per j4-column

typedef unsigned char u8;

__device__ __forceinline__ float4 f4add(float4 a, float4 b) {
    return make_float4(a.x + b.x, a.y + b.y, a.z + b.z, a.w + b.w);
}
// Exact expression shape of the verified kernel: ((ax*bx + ay*by) + az*bz) + aw*bw
__device__ __forceinline__ float dot4(float4 a, float4 b) {
    return a.x * b.x + a.y * b.y + a.z * b.z + a.w * b.w;
}

// ---------------------------------------------------------------------------
// Phase A. Round-5 post-mortem: the invariant 52-us floor tracks the v-loop's
// 64-lane BROADCAST ds_read_b128 of x (8 per j-step): a wave64 b128 delivers
// 1024 B through the ~128 B/clk LDS return bus even when all lanes read the
// same address -> ~4096 broadcast reads/CU saturate the per-CU LDS bus,
// independent of occupancy/gather/prefetch (matches rounds 0-5). Fix: invert
// the operands. w1 lives in LDS transposed ([j4][r], stride 65 float4) so
// lane r reads a DISTINCT contiguous float4 (bank-floor, 1 read per j-step,
// 8x less LDS traffic); x values are wave-uniform and sourced via
// readfirstlane-marked pointers -> scalar SMEM loads (no LDS, no VMEM
// vector). w1 slices are double-buffered with 8 named prefetch registers.
// Per-token summation order is bitwise-identical (same products, j-asc).
// ---------------------------------------------------------------------------
__global__ __launch_bounds__(128, 2) void phaseA(
    const float* __restrict__ x, const float* __restrict__ map_w,
    const float* __restrict__ map_b, const float* __restrict__ w1,
    u8* __restrict__ q_out, float* __restrict__ v_out,
    float* __restrict__ loss_out)
{
    const int t    = threadIdx.x;
    const int tok0 = blockIdx.x * TPB_A;
    __shared__ __align__(16) float  xs[TPB_A * XROW];      // 33,024 B
    __shared__ __align__(16) float4 wt[2][SLJ * WSTR];     // 33,280 B

    // ---- stage x tile (16 independent float4 loads/thread, coalesced) ----
    const float4* xsrc = (const float4*)(x + (size_t)tok0 * CDIM);
    #pragma unroll
    for (int i = t; i < TPB_A * (CDIM / 4); i += 128) {
        int r = i >> 7, c = i & 127;                    // CDIM/4 = 128
        *((float4*)(xs + r * XROW) + c) = xsrc[i];
    }

    // ---- w1 slice addressing: thread owns 8 float4/slice ----
    // i = k*128 + t -> row r = k*8 + (t>>4), col c = t&15 (slice-local)
    const float4* w1g = (const float4*)w1;              // [64][128] float4
    const int cc = t & 15;
    const int rr = t >> 4;                              // 0..7
    const float4* wgb = w1g + rr * 128 + cc;            // + k*1024 + s*16
    // prefetch slice 0 (in flight across the logits phase)
    float4 P0 = wgb[0 * 1024], P1 = wgb[1 * 1024], P2 = wgb[2 * 1024],
           P3 = wgb[3 * 1024], P4 = wgb[4 * 1024], P5 = wgb[5 * 1024],
           P6 = wgb[6 * 1024], P7 = wgb[7 * 1024];

    __syncthreads();

    // ---- logits: one thread per (token,bit), full-C f64 accumulation ----
    // (verbatim from the verified round-3 kernel; map_w is 16 KB = L1-hot)
    {
        const int bit = t & 7, tk = t >> 3;             // tk in 0..15
        const float4* m4 = (const float4*)(map_w + (size_t)bit * CDIM);
        const float4* x4 = (const float4*)xs + tk * XROW4;
        double a0 = 0.0, a1 = 0.0;
        for (int j = 0; j < CDIM / 4; ++j) {
            float4 m = m4[j], xv = x4[j];
            a0 += (double)m.x * (double)xv.x + (double)m.y * (double)xv.y;
            a1 += (double)m.z * (double)xv.z + (double)m.w * (double)xv.w;
        }
        double k = a0 + a1 + (double)map_b[bit];
        unsigned long long m = __ballot(k > 0.0);
        const int lane = t & 63;
        if ((lane & 7) == 0) {
            int g = lane >> 3;                          // local token in wave
            q_out[tok0 + tk] = (u8)((m >> (g * 8)) & 0xFFull);
        }
    }

    // ---- v: lane r = w1 row (from LDS, distinct), x uniform (scalar) ----
    {
        const int r   = t & 63;
        const int tg  = t >> 6;                         // 0..1
        const int tgu = __builtin_amdgcn_readfirstlane(tg);   // wave-uniform
        const float* xb = x + (size_t)(tok0 + tgu * 8) * CDIM;
        const float4* xr0 = (const float4*)(xb + 0 * CDIM);
        const float4* xr1 = (const float4*)(xb + 1 * CDIM);
        const float4* xr2 = (const float4*)(xb + 2 * CDIM);
        const float4* xr3 = (const float4*)(xb + 3 * CDIM);
        const float4* xr4 = (const float4*)(xb + 4 * CDIM);
        const float4* xr5 = (const float4*)(xb + 5 * CDIM);
        const float4* xr6 = (const float4*)(xb + 6 * CDIM);
        const float4* xr7 = (const float4*)(xb + 7 * CDIM);
        float acc0 = 0.f, acc1 = 0.f, acc2 = 0.f, acc3 = 0.f;
        float acc4 = 0.f, acc5 = 0.f, acc6 = 0.f, acc7 = 0.f;

        for (int s = 0; s < NSLICE; ++s) {
            // publish slice s: write addr = c*65 + k*8 + rr (bank-floor)
            float4* wb = &wt[s & 1][0];
            wb[cc * WSTR + 0 * 8 + rr] = P0;
            wb[cc * WSTR + 1 * 8 + rr] = P1;
            wb[cc * WSTR + 2 * 8 + rr] = P2;
            wb[cc * WSTR + 3 * 8 + rr] = P3;
            wb[cc * WSTR + 4 * 8 + rr] = P4;
            wb[cc * WSTR + 5 * 8 + rr] = P5;
            wb[cc * WSTR + 6 * 8 + rr] = P6;
            wb[cc * WSTR + 7 * 8 + rr] = P7;
            // prefetch slice s+1 (covered by this slice's compute)
            if (s + 1 < NSLICE) {
                const int go = (s + 1) * SLJ;
                P0 = wgb[0 * 1024 + go]; P1 = wgb[1 * 1024 + go];
                P2 = wgb[2 * 1024 + go]; P3 = wgb[3 * 1024 + go];
                P4 = wgb[4 * 1024 + go]; P5 = wgb[5 * 1024 + go];
                P6 = wgb[6 * 1024 + go]; P7 = wgb[7 * 1024 + go];
            }
            __syncthreads();
            #pragma unroll
            for (int jj = 0; jj < SLJ; ++jj) {
                const int j4 = s * SLJ + jj;            // global j, ascending
                float4 wv = wb[jj * WSTR + r];          // distinct/lane, contig
                float4 x0 = xr0[j4], x1 = xr1[j4], x2 = xr2[j4], x3 = xr3[j4];
                float4 x4v = xr4[j4], x5 = xr5[j4], x6 = xr6[j4], x7 = xr7[j4];
                acc0 += dot4(wv, x0);  acc1 += dot4(wv, x1);
                acc2 += dot4(wv, x2);  acc3 += dot4(wv, x3);
                acc4 += dot4(wv, x4v); acc5 += dot4(wv, x5);
                acc6 += dot4(wv, x6);  acc7 += dot4(wv, x7);
            }
        }

        float* vo = v_out + (size_t)(tok0 + tg * 8) * RD + r;   // coalesced
        vo[0 * RD] = acc0; vo[1 * RD] = acc1; vo[2 * RD] = acc2; vo[3 * RD] = acc3;
        vo[4 * RD] = acc4; vo[5 * RD] = acc5; vo[6 * RD] = acc6; vo[7 * RD] = acc7;
    }

    if (blockIdx.x == 0 && t == 0) loss_out[0] = 0.0f;  // loss = 0
}

// ---------------------------------------------------------------------------
// Phase B: verbatim from the round-3 kernel. 4 blocks per code, q_arr into
// registers first, 32 named weight float4s in flight across the scan,
// inner loop on 16 named fused-weight registers.
// ---------------------------------------------------------------------------
__global__ __launch_bounds__(128, 2) void phaseB(
    const u8* __restrict__ q_arr, const float* __restrict__ v_arr,
    const float* __restrict__ w21, const float* __restrict__ w22,
    const float* __restrict__ pwB, float* __restrict__ y)
{
    const int q  = blockIdx.x >> 2;
    const int qu = blockIdx.x & 3;
    const int t  = threadIdx.x;
    const int o  = qu * 128 + t;

    __shared__ unsigned short list[NTOK];   // 16 KB (worst case: all tokens one code)
    __shared__ int cnt;
    __shared__ __align__(16) float vs[8 * RD];  // 2 KB

    // ---- 1. q_arr into registers FIRST (retires before the weight burst) ----
    const uint4* qa = (const uint4*)q_arr;
    uint4 qv0 = qa[t], qv1 = qa[t + 128], qv2 = qa[t + 256], qv3 = qa[t + 384];

    // ---- 2. issue fused-weight loads (in flight during the scan) ----
    const float4* pa = (const float4*)w21 + (size_t)q * (OD * RD / 4) + (size_t)o * (RD / 4);
    const float4* pb = (const float4*)w22 + (size_t)(255 - q) * (OD * RD / 4) + (size_t)o * (RD / 4);
    float4 a0 = pa[0],  a1 = pa[1],  a2 = pa[2],  a3 = pa[3],
           a4 = pa[4],  a5 = pa[5],  a6 = pa[6],  a7 = pa[7],
           a8 = pa[8],  a9 = pa[9],  a10 = pa[10], a11 = pa[11],
           a12 = pa[12], a13 = pa[13], a14 = pa[14], a15 = pa[15];
    float4 b0 = pb[0],  b1 = pb[1],  b2 = pb[2],  b3 = pb[3],
           b4 = pb[4],  b5 = pb[5],  b6 = pb[6],  b7 = pb[7],
           b8 = pb[8],  b9 = pb[9],  b10 = pb[10], b11 = pb[11],
           b12 = pb[12], b13 = pb[13], b14 = pb[14], b15 = pb[15];

    if (t == 0) cnt = 0;
    __syncthreads();

    // ---- 3. scan from registers, LDS atomic append ----
#define CHK(WORD, SB, OFF) { unsigned uw = (WORD); \
    if ((int)(uw & 0xFFu)         == q) list[atomicAdd(&cnt, 1)] = (unsigned short)((SB) + (OFF));     \
    if ((int)((uw >> 8)  & 0xFFu) == q) list[atomicAdd(&cnt, 1)] = (unsigned short)((SB) + (OFF) + 1); \
    if ((int)((uw >> 16) & 0xFFu) == q) list[atomicAdd(&cnt, 1)] = (unsigned short)((SB) + (OFF) + 2); \
    if ((int)(uw >> 24)           == q) list[atomicAdd(&cnt, 1)] = (unsigned short)((SB) + (OFF) + 3); }
    { int sb = t * 16;          CHK(qv0.x, sb, 0) CHK(qv0.y, sb, 4) CHK(qv0.z, sb, 8) CHK(qv0.w, sb, 12) }
    { int sb = (t + 128) * 16;  CHK(qv1.x, sb, 0) CHK(qv1.y, sb, 4) CHK(qv1.z, sb, 8) CHK(qv1.w, sb, 12) }
    { int sb = (t + 256) * 16;  CHK(qv2.x, sb, 0) CHK(qv2.y, sb, 4) CHK(qv2.z, sb, 8) CHK(qv2.w, sb, 12) }
    { int sb = (t + 384) * 16;  CHK(qv3.x, sb, 0) CHK(qv3.y, sb, 4) CHK(qv3.z, sb, 8) CHK(qv3.w, sb, 12) }
#undef CHK
    __syncthreads();
    const int n = cnt;
    if (n == 0) return;                                 // uniform exit, no later syncs

    // ---- 4. combine fused weights into 16 named registers ----
    float4 w0 = f4add(a0, b0),  w1 = f4add(a1, b1),  w2 = f4add(a2, b2),  w3 = f4add(a3, b3),
           w4 = f4add(a4, b4),  w5 = f4add(a5, b5),  w6 = f4add(a6, b6),  w7 = f4add(a7, b7),
           w8 = f4add(a8, b8),  w9 = f4add(a9, b9),  w10 = f4add(a10, b10), w11 = f4add(a11, b11),
           w12 = f4add(a12, b12), w13 = f4add(a13, b13), w14 = f4add(a14, b14), w15 = f4add(a15, b15);
    const float bias = pwB[o];

    // ---- 5. stream tokens in batches of 8, token pairs (2 acc chains) ----
    const float4* v4 = (const float4*)v_arr;
    for (int base = 0; base < n; base += 8) {
        const int nb = min(8, n - base);
        if (t < nb * 16)                                // 8 tok x 16 float4 = 128 loads
            ((float4*)vs)[t] = v4[(size_t)list[base + (t >> 4)] * (RD / 4) + (t & 15)];
        __syncthreads();
        int i = 0;
        for (; i + 2 <= nb; i += 2) {
            const float4* p0 = (const float4*)vs + (size_t)i * 16;
            const float4* p1 = p0 + 16;
            float acc0 = bias, acc1 = bias;
#define STEP(J, W) { float4 u0 = p0[J], u1 = p1[J]; \
            acc0 += W.x * u0.x + W.y * u0.y + W.z * u0.z + W.w * u0.w; \
            acc1 += W.x * u1.x + W.y * u1.y + W.z * u1.z + W.w * u1.w; }
            STEP(0, w0)  STEP(1, w1)  STEP(2, w2)  STEP(3, w3)
            STEP(4, w4)  STEP(5, w5)  STEP(6, w6)  STEP(7, w7)
            STEP(8, w8)  STEP(9, w9)  STEP(10, w10) STEP(11, w11)
            STEP(12, w12) STEP(13, w13) STEP(14, w14) STEP(15, w15)
#undef STEP
            y[(size_t)list[base + i]     * OD + o] = acc0;
            y[(size_t)list[base + i + 1] * OD + o] = acc1;
        }
        if (i < nb) {                                   // odd tail
            const float4* p0 = (const float4*)vs + (size_t)i * 16;
            float acc0 = bias;
#define STEP1(J, W) { float4 u0 = p0[J]; \
            acc0 += W.x * u0.x + W.y * u0.y + W.z * u0.z + W.w * u0.w; }
            STEP1(0, w0)  STEP1(1, w1)  STEP1(2, w2)  STEP1(3, w3)
            STEP1(4, w4)  STEP1(5, w5)  STEP1(6, w6)  STEP1(7, w7)
            STEP1(8, w8)  STEP1(9, w9)  STEP1(10, w10) STEP1(11, w11)
            STEP1(12, w12) STEP1(13, w13) STEP1(14, w14) STEP1(15, w15)
#undef STEP1
            y[(size_t)list[base + i] * OD + o] = acc0;
        }
        __syncthreads();
    }
}

// ---------------------------------------------------------------------------
// Fallback (ws too small): workspace-free, one block per token.
// ---------------------------------------------------------------------------
__global__ __launch_bounds__(256) void mono(
    const float* __restrict__ x, const float* __restrict__ map_w,
    const float* __restrict__ map_b, const float* __restrict__ w1,
    const float* __restrict__ w21, const float* __restrict__ w22,
    const float* __restrict__ pwB, float* __restrict__ y)
{
    const int tok = blockIdx.x;
    const int t   = threadIdx.x;
    __shared__ float xsh[CDIM];
    __shared__ float vsh[RD];
    __shared__ int qsh;

    if (t == 0) qsh = 0;
    for (int i = t; i < CDIM; i += 256) xsh[i] = x[(size_t)tok * CDIM + i];
    __syncthreads();

    if (t < NB) {
        double a = 0.0;
        const float* mrow = map_w + (size_t)t * CDIM;
        for (int j = 0; j < CDIM; ++j) a += (double)mrow[j] * (double)xsh[j];
        a += (double)map_b[t];
        if (a > 0.0) atomicOr(&qsh, 1 << t);
    }
    if (t < RD) {
        const float* wrow = w1 + (size_t)t * CDIM;
        float acc = 0.f;
        for (int j = 0; j < CDIM; ++j) acc += wrow[j] * xsh[j];
        vsh[t] = acc;
    }
    __syncthreads();

    const int q = qsh;
    for (int o = t; o < OD; o += 256) {
        const float* pa = w21 + (size_t)q * (OD * RD) + (size_t)o * RD;
        const float* pb = w22 + (size_t)(255 - q) * (OD * RD) + (size_t)o * RD;
        float acc = pwB[o];
        for (int r = 0; r < RD; ++r) acc += (pa[r] + pb[r]) * vsh[r];
        y[(size_t)tok * OD + o] = acc;
    }
    if (tok == 0 && t == 0) y[(size_t)NTOK * OD] = 0.0f;
}

extern "C" void kernel_launch(void* const* d_in, const int* in_sizes, int n_in,
                              void* d_out, int out_size, void* d_ws, size_t ws_size,
                              hipStream_t stream) {
    const float* x     = (const float*)d_in[0];
    // d_in[1] = key: unused by the forward pass
    const float* map_w = (const float*)d_in[2];
    const float* map_b = (const float*)d_in[3];
    const float* w1    = (const float*)d_in[4];
    const float* w21   = (const float*)d_in[5];
    const float* w22   = (const float*)d_in[6];
    const float* pwB   = (const float*)d_in[7];
    float* out = (float*)d_out;

    const size_t need = (size_t)NTOK + (size_t)NTOK * RD * sizeof(float); // 8KB + 2MB
    if (ws_size >= need) {
        u8*    q_ws = (u8*)d_ws;
        float* v_ws = (float*)((char*)d_ws + NTOK);
        phaseA<<<NTOK / TPB_A, 128, 0, stream>>>(x, map_w, map_b, w1, q_ws, v_ws,
                                                 out + (size_t)NTOK * OD);
        phaseB<<<256 * 4, 128, 0, stream>>>(q_ws, v_ws, w21, w22, pwB, out);
    } else {
        mono<<<NTOK, 256, 0, stream>>>(x, map_w, map_b, w1, w21, w22, pwB, out);
    }
}